// Round 4
// baseline (9555.669 us; speedup 1.0000x reference)
//
#include <hip/hip_runtime.h>
#include <hip/hip_fp16.h>
#include <cstddef>

#define Bb 64
#define Tt 512
#define INRAW 225
#define INPAD 240
#define Hh 256
#define G4 1024
#define Ee 512
#define NCODE 128
#define NCLS 250

typedef _Float16 half8_t __attribute__((ext_vector_type(8)));
typedef float f32x4 __attribute__((ext_vector_type(4)));

__device__ __forceinline__ float sigf(float x) { return 1.0f / (1.0f + expf(-x)); }
// fast versions (v_exp_f32 + v_rcp_f32): abs err ~1e-7, fine at 22x headroom
__device__ __forceinline__ float fsig(float x) { return __builtin_amdgcn_rcpf(1.0f + __expf(-x)); }
__device__ __forceinline__ float ftanh(float x) {
  return 2.0f * __builtin_amdgcn_rcpf(1.0f + __expf(-2.0f * x)) - 1.0f;
}

// ---------------- pad copy: [M,Ks] -> [M,Kd] zero-filled ----------------
__global__ __launch_bounds__(256) void pad_copy_k(const float* __restrict__ src,
                                                  float* __restrict__ dst,
                                                  int M, int Ks, int Kd) {
  long long idx = (long long)blockIdx.x * 256 + threadIdx.x;
  if (idx >= (long long)M * Kd) return;
  int m = (int)(idx / Kd);
  int k = (int)(idx - (long long)m * Kd);
  dst[idx] = (k < Ks) ? src[(long long)m * Ks + k] : 0.0f;
}

// ------- pack W[1024,K] -> wp[k][j(0..255)][g(0..3)] fp32 (dec_bwd only) ------
__global__ __launch_bounds__(256) void pack_w_k(const float* __restrict__ W,
                                                float* __restrict__ wp, int K) {
  int idx = blockIdx.x * 256 + threadIdx.x;   // = jg*K + k
  int jg = idx / K;
  if (jg >= 1024) return;
  int k = idx - jg * K;
  int j = jg >> 2, g = jg & 3;
  wp[(((size_t)k << 8) + j) * 4 + g] = W[(size_t)(g * 256 + j) * K + k];
}

// ------- pack Whh[1024,256] fp32 -> fp16 MFMA B-fragment stream ---------------
// flat half idx = ((((wv*8+ks)*8)+zg)*64 + l)*8 + e
// value = Whh[(g*256 + u)*256 + k], zg=z*4+g, u=wv*32+z*16+(l&15), k=ks*32+(l>>4)*8+e
__global__ __launch_bounds__(256) void pack_w_frag(const float* __restrict__ W,
                                                   _Float16* __restrict__ wp) {
  int idx = blockIdx.x * 256 + threadIdx.x;   // 262144 total
  int e = idx & 7, l = (idx >> 3) & 63, zg = (idx >> 9) & 7;
  int ks = (idx >> 12) & 7, wv = (idx >> 15) & 7;
  int z = zg >> 2, g = zg & 3;
  int u = wv * 32 + z * 16 + (l & 15);
  int k = ks * 32 + (l >> 4) * 8 + e;
  wp[idx] = (_Float16)W[(size_t)(g * 256 + u) * 256 + k];
}

// ---- GEMM: C[M,N] = A[M,K] @ Bw[N,K]^T + bias[N]; fp16 out in the scan's
// per-lane fragment order (see lstm_scan_mfma pre layout).
#define BM 128
#define BN 128
#define BKk 16
__global__ __launch_bounds__(256) void gemm_nt_bias_h(const float* __restrict__ A,
                                                      const float* __restrict__ Bw,
                                                      const float* __restrict__ bias,
                                                      __half* __restrict__ C,
                                                      int M, int N, int K) {
  __shared__ __align__(16) float As[BKk][BM];
  __shared__ __align__(16) float Bs[BKk][BN];
  const int tid = threadIdx.x;
  const int bm = blockIdx.y * BM, bn = blockIdx.x * BN;
  const int ty = tid >> 4, tx = tid & 15;
  const int srow = tid >> 1;
  const int sk = (tid & 1) * 8;

  const float* Aptr = A + (size_t)(bm + srow) * K + sk;
  const float* Bptr = Bw + (size_t)(bn + srow) * K + sk;

  float4 ra0 = *(const float4*)(Aptr);
  float4 ra1 = *(const float4*)(Aptr + 4);
  float4 rb0 = *(const float4*)(Bptr);
  float4 rb1 = *(const float4*)(Bptr + 4);

  float acc[8][8];
#pragma unroll
  for (int i = 0; i < 8; ++i)
#pragma unroll
    for (int j = 0; j < 8; ++j) acc[i][j] = 0.0f;

  for (int k0 = 0; k0 < K; k0 += BKk) {
    __syncthreads();
    As[sk + 0][srow] = ra0.x; As[sk + 1][srow] = ra0.y;
    As[sk + 2][srow] = ra0.z; As[sk + 3][srow] = ra0.w;
    As[sk + 4][srow] = ra1.x; As[sk + 5][srow] = ra1.y;
    As[sk + 6][srow] = ra1.z; As[sk + 7][srow] = ra1.w;
    Bs[sk + 0][srow] = rb0.x; Bs[sk + 1][srow] = rb0.y;
    Bs[sk + 2][srow] = rb0.z; Bs[sk + 3][srow] = rb0.w;
    Bs[sk + 4][srow] = rb1.x; Bs[sk + 5][srow] = rb1.y;
    Bs[sk + 6][srow] = rb1.z; Bs[sk + 7][srow] = rb1.w;
    __syncthreads();
    if (k0 + BKk < K) {
      ra0 = *(const float4*)(Aptr + k0 + BKk);
      ra1 = *(const float4*)(Aptr + k0 + BKk + 4);
      rb0 = *(const float4*)(Bptr + k0 + BKk);
      rb1 = *(const float4*)(Bptr + k0 + BKk + 4);
    }
#pragma unroll
    for (int kk = 0; kk < BKk; ++kk) {
      float4 aA = *(const float4*)&As[kk][ty * 8];
      float4 aB = *(const float4*)&As[kk][ty * 8 + 4];
      float4 bA = *(const float4*)&Bs[kk][tx * 8];
      float4 bB = *(const float4*)&Bs[kk][tx * 8 + 4];
      float av[8] = {aA.x, aA.y, aA.z, aA.w, aB.x, aB.y, aB.z, aB.w};
      float bv[8] = {bA.x, bA.y, bA.z, bA.w, bB.x, bB.y, bB.z, bB.w};
#pragma unroll
      for (int i = 0; i < 8; ++i)
#pragma unroll
        for (int j = 0; j < 8; ++j)
          acc[i][j] = fmaf(av[i], bv[j], acc[i][j]);
    }
  }
  float bs[8];
#pragma unroll
  for (int j = 0; j < 8; ++j) bs[j] = bias[bn + tx * 8 + j];

  // scatter into scan fragment layout:
  // half idx = ((((t*4+b)*8+w)*2+z)*64 + lane)*16 + g*4 + j
  const int col0 = bn + tx * 8;
  const int g = col0 >> 8;
  const int u0 = col0 & 255;                 // 8-aligned
  const int w_ = u0 >> 5, z_ = (u0 >> 4) & 1, l15_ = u0 & 15;
#pragma unroll
  for (int i = 0; i < 8; ++i) {
    const int row = bm + ty * 8 + i;
    const int t = row & (Tt - 1);
    const int batch = row >> 9;
    const int b_ = batch >> 4, rbq = (batch & 15) >> 2, j_ = batch & 3;
    const int lane = (rbq << 4) | l15_;
    __half* dst = C + ((((size_t)t * 4 + b_) * 8 + w_) * 2 + z_) * 1024
                    + (size_t)lane * 16 + g * 4 + j_;
#pragma unroll
    for (int jx = 0; jx < 8; ++jx) dst[jx * 16] = __float2half(acc[i][jx] + bs[jx]);
  }
}

// -------------- MFMA LSTM scan: 1 block = 16 rows, 512 threads (8 waves) ------
// wave wv owns units [wv*32, wv*32+32) (2 unit-slices z). Per step:
// gates[16 x 1024] = pre + h(t-1) @ Whh^T via 64 mfma_16x16x32_f16 per wave.
// h kept fp16 in LDS (XOR-swizzled), double buffered; c in VGPRs.
__global__ __launch_bounds__(512) void lstm_scan_mfma(
    const half8_t* __restrict__ preF, const half8_t* __restrict__ wF, float* __restrict__ hF,
    const half8_t* __restrict__ preB, const half8_t* __restrict__ wB, float* __restrict__ hB,
    int nfwd) {
  const int isB = (blockIdx.x >= nfwd) ? 1 : 0;
  const half8_t* pre = isB ? preB : preF;
  const half8_t* wfrag = isB ? wB : wF;
  float* hout = isB ? hB : hF;
  const int blk = blockIdx.x - (isB ? nfwd : 0);   // 0..3 -> rows 16*blk..
  const int tid = threadIdx.x;
  const int wv = tid >> 6;
  const int l = tid & 63;
  const int l15 = l & 15, lg = l >> 4;

  __shared__ __align__(16) char hbuf[2][16 * 256 * 2];   // 16 KB total

  {
    uint4* p = (uint4*)hbuf;
    for (int i = tid; i < (int)(sizeof(hbuf) / 16); i += 512)
      p[i] = make_uint4(0u, 0u, 0u, 0u);
  }

  float c[2][4] = {{0.f, 0.f, 0.f, 0.f}, {0.f, 0.f, 0.f, 0.f}};
  const int swzA = (l15 & 7) << 4;
  const size_t pre_wz = (size_t)(blk * 8 + wv);
  const size_t wbase = (size_t)wv * 64;   // half8 units

  half8_t pcur[2][2];
  {
    const int t0 = isB ? (Tt - 1) : 0;
    const size_t bb = (((size_t)t0 * 32 + pre_wz) * 2) * 128 + (size_t)l * 2;
#pragma unroll
    for (int z = 0; z < 2; ++z)
#pragma unroll
      for (int h8 = 0; h8 < 2; ++h8)
        pcur[z][h8] = pre[bb + z * 128 + h8];
  }

  for (int s = 0; s < Tt; ++s) {
    const int t = isB ? (Tt - 1 - s) : s;

    // acc init from prefetched pre (C/D layout: col=l&15 -> unit, row=lg*4+j -> batch row)
    f32x4 acc[2][4];
#pragma unroll
    for (int z = 0; z < 2; ++z)
#pragma unroll
      for (int g = 0; g < 4; ++g)
#pragma unroll
        for (int j = 0; j < 4; ++j)
          acc[z][g][j] = (float)pcur[z][g >> 1][(g & 1) * 4 + j];

    // B ring prologue (groups 0..2); weights are step-invariant, L2-resident
    half8_t bfr[3][8];
#pragma unroll
    for (int ks = 0; ks < 3; ++ks)
#pragma unroll
      for (int zg = 0; zg < 8; ++zg)
        bfr[ks][zg] = wfrag[(wbase + ks * 8 + zg) * 64 + l];

    // prefetch next step's pre (overlaps barrier + mfma)
    if (s + 1 < Tt) {
      const int tn = isB ? (Tt - 2 - s) : (s + 1);
      const size_t bb = (((size_t)tn * 32 + pre_wz) * 2) * 128 + (size_t)l * 2;
#pragma unroll
      for (int z = 0; z < 2; ++z)
#pragma unroll
        for (int h8 = 0; h8 < 2; ++h8)
          pcur[z][h8] = pre[bb + z * 128 + h8];
    }

    __syncthreads();   // h(t-1) writes visible

    // A fragments: row = l&15, k = ks*32 + lg*8 + e (consistent with B pack)
    const char* rbuf = hbuf[s & 1];
    half8_t afr[8];
#pragma unroll
    for (int ks = 0; ks < 8; ++ks) {
      const int byte = (l15 * 512 + ks * 64 + lg * 16) ^ swzA;
      afr[ks] = *(const half8_t*)(rbuf + byte);
    }

#pragma unroll
    for (int ks = 0; ks < 8; ++ks) {
#pragma unroll
      for (int zg = 0; zg < 8; ++zg)
        acc[zg >> 2][zg & 3] = __builtin_amdgcn_mfma_f32_16x16x32_f16(
            afr[ks], bfr[ks % 3][zg], acc[zg >> 2][zg & 3], 0, 0, 0);
      if (ks + 3 < 8) {
#pragma unroll
        for (int zg = 0; zg < 8; ++zg)
          bfr[(ks + 3) % 3][zg] = wfrag[(wbase + (ks + 3) * 8 + zg) * 64 + l];
      }
    }

    // gates -> c,h (all 4 gates of (row,unit) are in-lane)
    char* wbuf = hbuf[(s + 1) & 1];
#pragma unroll
    for (int z = 0; z < 2; ++z) {
      const int u = wv * 32 + z * 16 + l15;
#pragma unroll
      for (int j = 0; j < 4; ++j) {
        const int r = lg * 4 + j;
        float iv = fsig(acc[z][0][j]);
        float fv = fsig(acc[z][1][j]);
        float gv = ftanh(acc[z][2][j]);
        float ov = fsig(acc[z][3][j]);
        c[z][j] = fv * c[z][j] + iv * gv;
        float hv = ov * ftanh(c[z][j]);
        const int byte = (r * 512 + u * 2) ^ ((r & 7) << 4);
        *(_Float16*)(wbuf + byte) = (_Float16)hv;
        hout[((size_t)(blk * 16 + r) * Tt + t) * Hh + u] = hv;
      }
    }
  }
}

// ---------------- VQ: 4 vectors/block, 128 threads (one code per thread) ------
#define VPB 4
__global__ __launch_bounds__(128) void vq_kernel(const float* __restrict__ hf,
                                                 const float* __restrict__ hb,
                                                 const float* __restrict__ cb,
                                                 float* __restrict__ q,
                                                 float* __restrict__ dmin) {
  const int tid = threadIdx.x;
  const int v0 = blockIdx.x * VPB;
  __shared__ __align__(16) float zs[VPB][Ee];
  __shared__ float dsh[NCODE];
  __shared__ int ish[NCODE];
  __shared__ int best[VPB];

#pragma unroll
  for (int v = 0; v < VPB; ++v) {
    size_t vb = (size_t)(v0 + v);
    zs[v][tid]       = hf[vb * Hh + tid];
    zs[v][tid + 128] = hf[vb * Hh + tid + 128];
    zs[v][tid + 256] = hb[vb * Hh + tid];
    zs[v][tid + 384] = hb[vb * Hh + tid + 128];
  }
  __syncthreads();

  float dv[VPB] = {0.0f, 0.0f, 0.0f, 0.0f};
  const float4* crow = (const float4*)(cb + (size_t)tid * Ee);
#pragma unroll 2
  for (int e4 = 0; e4 < Ee / 4; ++e4) {
    float4 cc = crow[e4];
#pragma unroll
    for (int v = 0; v < VPB; ++v) {
      float4 z = *(const float4*)&zs[v][e4 * 4];
      float t0 = z.x - cc.x, t1 = z.y - cc.y, t2 = z.z - cc.z, t3 = z.w - cc.w;
      dv[v] = fmaf(t0, t0, dv[v]);
      dv[v] = fmaf(t1, t1, dv[v]);
      dv[v] = fmaf(t2, t2, dv[v]);
      dv[v] = fmaf(t3, t3, dv[v]);
    }
  }

#pragma unroll
  for (int v = 0; v < VPB; ++v) {
    __syncthreads();
    dsh[tid] = dv[v];
    ish[tid] = tid;
    __syncthreads();
    for (int off = 64; off > 0; off >>= 1) {
      if (tid < off) {
        float dn = dsh[tid + off];
        int in_ = ish[tid + off];
        if (dn < dsh[tid] || (dn == dsh[tid] && in_ < ish[tid])) {
          dsh[tid] = dn;
          ish[tid] = in_;
        }
      }
      __syncthreads();
    }
    if (tid == 0) {
      best[v] = ish[0];
      dmin[v0 + v] = dsh[0];
    }
  }
  __syncthreads();

#pragma unroll
  for (int v = 0; v < VPB; ++v) {
    const float* cbest = cb + (size_t)best[v] * Ee;
    float* qrow = q + (size_t)(v0 + v) * Ee;
#pragma unroll
    for (int u = 0; u < 4; ++u) {
      int e = tid + u * 128;
      float z = zs[v][e];
      qrow[e] = z + (cbest[e] - z);
    }
  }
}

// ---------------- vq loss reduce ----------------
__global__ __launch_bounds__(256) void vq_reduce(const float* __restrict__ dmin,
                                                 float* __restrict__ out) {
  __shared__ float sh[256];
  int tid = threadIdx.x;
  float s = 0.0f;
  for (int i = tid; i < Bb * Tt; i += 256) s += dmin[i];
  sh[tid] = s;
  __syncthreads();
  for (int off = 128; off > 0; off >>= 1) {
    if (tid < off) sh[tid] += sh[tid + off];
    __syncthreads();
  }
  if (tid == 0) out[Bb * NCLS] = sh[0] * (1.25f / ((float)(Bb * Tt) * (float)Ee));
}

// ---------------- decoder backward, single step at t=T-1 (h_prev=c_prev=0) ----
__global__ __launch_bounds__(256) void dec_bwd_last(const float* __restrict__ q,
                                                    const float* __restrict__ wpB,  // [512][256][4]
                                                    const float* __restrict__ bias,
                                                    float* __restrict__ hb_last) {
  int b = blockIdx.x, tid = threadIdx.x;
  __shared__ __align__(16) float zsl[Ee];
  const float* qrow = q + ((size_t)b * Tt + (Tt - 1)) * Ee;
  zsl[tid] = qrow[tid];
  zsl[tid + 256] = qrow[tid + 256];
  __syncthreads();
  float a0 = bias[tid], a1 = bias[256 + tid], a2 = bias[512 + tid], a3 = bias[768 + tid];
  const float4* wp4 = (const float4*)wpB;
#pragma unroll 4
  for (int k = 0; k < Ee; ++k) {
    float zk = zsl[k];
    float4 w = wp4[((size_t)k << 8) + tid];
    a0 = fmaf(zk, w.x, a0); a1 = fmaf(zk, w.y, a1);
    a2 = fmaf(zk, w.z, a2); a3 = fmaf(zk, w.w, a3);
  }
  float i = sigf(a0), f = sigf(a1), g = tanhf(a2), o = sigf(a3);
  (void)f;
  float cc = i * g;
  hb_last[b * Hh + tid] = o * tanhf(cc);
}

// ---------------- classifier ----------------
__global__ __launch_bounds__(256) void classifier_k(const float* __restrict__ dec_hf,
                                                    const float* __restrict__ hb_last,
                                                    const float* __restrict__ Wcls,
                                                    const float* __restrict__ bcls,
                                                    float* __restrict__ out) {
  int b = blockIdx.x, tid = threadIdx.x;
  __shared__ __align__(16) float dl[Ee];
  dl[tid] = dec_hf[((size_t)b * Tt + (Tt - 1)) * Hh + tid];
  dl[tid + 256] = hb_last[b * Hh + tid];
  __syncthreads();
  if (tid < NCLS) {
    const float4* wr = (const float4*)(Wcls + (size_t)tid * Ee);
    float acc = bcls[tid];
#pragma unroll 4
    for (int e4 = 0; e4 < Ee / 4; ++e4) {
      float4 w = wr[e4];
      float4 z = *(const float4*)&dl[e4 * 4];
      acc = fmaf(w.x, z.x, acc);
      acc = fmaf(w.y, z.y, acc);
      acc = fmaf(w.z, z.z, acc);
      acc = fmaf(w.w, z.w, acc);
    }
    out[b * NCLS + tid] = acc;
  }
}

// ---------------- launch ----------------
extern "C" void kernel_launch(void* const* d_in, const int* in_sizes, int n_in,
                              void* d_out, int out_size, void* d_ws, size_t ws_size,
                              hipStream_t stream) {
  const float* x     = (const float*)d_in[0];
  const float* eWihF = (const float*)d_in[1];
  const float* eWhhF = (const float*)d_in[2];
  const float* ebF   = (const float*)d_in[3];
  const float* eWihB = (const float*)d_in[4];
  const float* eWhhB = (const float*)d_in[5];
  const float* ebB   = (const float*)d_in[6];
  const float* cb    = (const float*)d_in[7];
  const float* dWihF = (const float*)d_in[8];
  const float* dWhhF = (const float*)d_in[9];
  const float* dbF   = (const float*)d_in[10];
  const float* dWihB = (const float*)d_in[11];
  // d_in[12] = dec_Whh_b: unused (backward decoder state at t=T-1 starts from zero)
  const float* dbB   = (const float*)d_in[13];
  const float* Wcls  = (const float*)d_in[14];
  const float* bcls  = (const float*)d_in[15];
  float* out = (float*)d_out;
  float* w = (float*)d_ws;

  const size_t MR = (size_t)Bb * Tt;                 // 32768
  const size_t SZ_PRE_H = MR * G4 / 2;               // fp16 pre buffer, float units
  const size_t SZ_EH   = MR * Hh;
  const size_t SZ_XPAD = MR * INPAD;
  const size_t SZ_WPAD = (size_t)G4 * INPAD;
  const size_t SZ_WPK  = (size_t)512 * G4;           // dec_bwd fp32 pack
  const size_t SZ_WPH  = (size_t)G4 * Hh / 2;        // 131072 floats = 512 KB frag pack
  const size_t SZ_TAIL = SZ_XPAD + 2 * SZ_WPAD + SZ_WPK + 3 * SZ_WPH + MR + (size_t)Bb * Hh;

  const size_t NEED_PAR = (2 * SZ_PRE_H + 2 * SZ_EH + SZ_TAIL) * 4;
  const bool par = ws_size >= NEED_PAR;

  __half *preFh, *preBh, *dprf;
  float *ehf, *ehb, *xpad, *wfpad, *wbpad, *wpkbd, *dminp, *hbl;
  _Float16 *wphF, *wphB, *wphD;
  float *quant, *dhf;
  size_t o = 0;
  if (par) {
    preFh = (__half*)(w + o); o += SZ_PRE_H;
    preBh = (__half*)(w + o); o += SZ_PRE_H;
    ehf = w + o; o += SZ_EH;
    ehb = w + o; o += SZ_EH;
    quant = (float*)preFh;       // over dead preF after scans
    dprf  = preBh;               // decoder pre over dead preB
    dhf   = ehf;                 // decoder h over dead ehf (post-VQ)
  } else {
    preFh = (__half*)(w + o); o += SZ_PRE_H;   // reused for preB as well
    preBh = preFh;
    ehf = w + o; o += SZ_EH;
    ehb = w + o; o += SZ_EH;
    quant = (float*)preFh;
    dprf  = (__half*)ehf;        // decoder pre over dead ehf+ehb (post-VQ)
    dhf   = (float*)preFh;       // over dead quant (after dec GEMM + dec_bwd_last)
  }
  xpad  = w + o; o += SZ_XPAD;
  wfpad = w + o; o += SZ_WPAD;
  wbpad = w + o; o += SZ_WPAD;
  wpkbd = w + o; o += SZ_WPK;
  wphF  = (_Float16*)(w + o); o += SZ_WPH;
  wphB  = (_Float16*)(w + o); o += SZ_WPH;
  wphD  = (_Float16*)(w + o); o += SZ_WPH;
  dminp = w + o; o += MR;
  hbl   = w + o; o += (size_t)Bb * Hh;

  // 1. prep: pads + packs
  hipLaunchKernelGGL(pad_copy_k, dim3((MR * INPAD) / 256), dim3(256), 0, stream,
                     x, xpad, (int)MR, INRAW, INPAD);
  hipLaunchKernelGGL(pad_copy_k, dim3((G4 * INPAD) / 256), dim3(256), 0, stream,
                     eWihF, wfpad, G4, INRAW, INPAD);
  hipLaunchKernelGGL(pad_copy_k, dim3((G4 * INPAD) / 256), dim3(256), 0, stream,
                     eWihB, wbpad, G4, INRAW, INPAD);
  hipLaunchKernelGGL(pack_w_k, dim3((G4 * 512) / 256), dim3(256), 0, stream, dWihB, wpkbd, 512);
  hipLaunchKernelGGL(pack_w_frag, dim3(1024), dim3(256), 0, stream, eWhhF, wphF);
  hipLaunchKernelGGL(pack_w_frag, dim3(1024), dim3(256), 0, stream, eWhhB, wphB);
  hipLaunchKernelGGL(pack_w_frag, dim3(1024), dim3(256), 0, stream, dWhhF, wphD);

  const dim3 gemmGrid(G4 / BN, MR / BM);
  if (par) {
    hipLaunchKernelGGL(gemm_nt_bias_h, gemmGrid, dim3(256), 0, stream,
                       xpad, wfpad, ebF, preFh, (int)MR, G4, INPAD);
    hipLaunchKernelGGL(gemm_nt_bias_h, gemmGrid, dim3(256), 0, stream,
                       xpad, wbpad, ebB, preBh, (int)MR, G4, INPAD);
    hipLaunchKernelGGL(lstm_scan_mfma, dim3(8), dim3(512), 0, stream,
                       (const half8_t*)preFh, (const half8_t*)wphF, ehf,
                       (const half8_t*)preBh, (const half8_t*)wphB, ehb, 4);
  } else {
    hipLaunchKernelGGL(gemm_nt_bias_h, gemmGrid, dim3(256), 0, stream,
                       xpad, wfpad, ebF, preFh, (int)MR, G4, INPAD);
    hipLaunchKernelGGL(lstm_scan_mfma, dim3(4), dim3(512), 0, stream,
                       (const half8_t*)preFh, (const half8_t*)wphF, ehf,
                       (const half8_t*)preFh, (const half8_t*)wphF, ehf, 4);
    hipLaunchKernelGGL(gemm_nt_bias_h, gemmGrid, dim3(256), 0, stream,
                       xpad, wbpad, ebB, preFh, (int)MR, G4, INPAD);
    hipLaunchKernelGGL(lstm_scan_mfma, dim3(4), dim3(512), 0, stream,
                       (const half8_t*)preFh, (const half8_t*)wphB, ehb,
                       (const half8_t*)preFh, (const half8_t*)wphB, ehb, 0);
  }

  // 4. VQ + loss
  hipLaunchKernelGGL(vq_kernel, dim3(MR / VPB), dim3(128), 0, stream,
                     ehf, ehb, cb, quant, dminp);
  hipLaunchKernelGGL(vq_reduce, dim3(1), dim3(256), 0, stream, dminp, out);

  // 5. decoder fwd input projection
  hipLaunchKernelGGL(gemm_nt_bias_h, gemmGrid, dim3(256), 0, stream,
                     quant, dWihF, dbF, dprf, (int)MR, G4, Ee);

  // 6. decoder bwd (only t=T-1 contributes; reads quant before dhf overwrites)
  hipLaunchKernelGGL(dec_bwd_last, dim3(Bb), dim3(256), 0, stream, quant, wpkbd, dbB, hbl);

  // 7. decoder fwd scan
  hipLaunchKernelGGL(lstm_scan_mfma, dim3(4), dim3(512), 0, stream,
                     (const half8_t*)dprf, (const half8_t*)wphD, dhf,
                     (const half8_t*)dprf, (const half8_t*)wphD, dhf, 4);

  // 8. classifier
  hipLaunchKernelGGL(classifier_k, dim3(Bb), dim3(256), 0, stream,
                     dhf, hbl, Wcls, bcls, out);
}

// Round 5
// 8569.100 us; speedup vs baseline: 1.1151x; 1.1151x over previous
//
#include <hip/hip_runtime.h>
#include <hip/hip_fp16.h>
#include <cstddef>

#define Bb 64
#define Tt 512
#define INRAW 225
#define INPAD 240
#define Hh 256
#define G4 1024
#define Ee 512
#define NCODE 128
#define NCLS 250

typedef _Float16 half8_t __attribute__((ext_vector_type(8)));
typedef float f32x4 __attribute__((ext_vector_type(4)));

__device__ __forceinline__ float sigf(float x) { return 1.0f / (1.0f + expf(-x)); }
__device__ __forceinline__ float fsig(float x) { return __builtin_amdgcn_rcpf(1.0f + __expf(-x)); }
__device__ __forceinline__ float ftanh(float x) {
  return 2.0f * __builtin_amdgcn_rcpf(1.0f + __expf(-2.0f * x)) - 1.0f;
}

// ---------------- zero flags (agent-scope stores: visible at coherence point) -
__global__ __launch_bounds__(256) void zero_flags_k(int* __restrict__ p, int n) {
  int i = blockIdx.x * 256 + threadIdx.x;
  if (i < n) __hip_atomic_store(&p[i], 0, __ATOMIC_RELAXED, __HIP_MEMORY_SCOPE_AGENT);
}

// ---------------- pad copy: [M,Ks] -> [M,Kd] zero-filled ----------------
__global__ __launch_bounds__(256) void pad_copy_k(const float* __restrict__ src,
                                                  float* __restrict__ dst,
                                                  int M, int Ks, int Kd) {
  long long idx = (long long)blockIdx.x * 256 + threadIdx.x;
  if (idx >= (long long)M * Kd) return;
  int m = (int)(idx / Kd);
  int k = (int)(idx - (long long)m * Kd);
  dst[idx] = (k < Ks) ? src[(long long)m * Ks + k] : 0.0f;
}

// ------- pack W[1024,K] -> wp[k][j(0..255)][g(0..3)] fp32 (dec_bwd only) ------
__global__ __launch_bounds__(256) void pack_w_k(const float* __restrict__ W,
                                                float* __restrict__ wp, int K) {
  int idx = blockIdx.x * 256 + threadIdx.x;   // = jg*K + k
  int jg = idx / K;
  if (jg >= 1024) return;
  int k = idx - jg * K;
  int j = jg >> 2, g = jg & 3;
  wp[(((size_t)k << 8) + j) * 4 + g] = W[(size_t)(g * 256 + j) * K + k];
}

// ------- pack Whh[1024,256] fp32 -> fp16 MFMA B-fragment stream ---------------
// flat half idx = ((((wv*8+ks)*8)+zg)*64 + l)*8 + e
// value = Whh[(g*256 + u)*256 + k], zg=z*4+g, u=wv*32+z*16+(l&15), k=ks*32+(l>>4)*8+e
__global__ __launch_bounds__(256) void pack_w_frag(const float* __restrict__ W,
                                                   _Float16* __restrict__ wp) {
  int idx = blockIdx.x * 256 + threadIdx.x;   // 262144 total
  int e = idx & 7, l = (idx >> 3) & 63, zg = (idx >> 9) & 7;
  int ks = (idx >> 12) & 7, wv = (idx >> 15) & 7;
  int z = zg >> 2, g = zg & 3;
  int u = wv * 32 + z * 16 + (l & 15);
  int k = ks * 32 + (l >> 4) * 8 + e;
  wp[idx] = (_Float16)W[(size_t)(g * 256 + u) * 256 + k];
}

// ---- GEMM: C[M,N] = A[M,K] @ Bw[N,K]^T + bias[N]; fp16 out in the scan's
// per-lane fragment order (verified R4).
#define BM 128
#define BN 128
#define BKk 16
__global__ __launch_bounds__(256) void gemm_nt_bias_h(const float* __restrict__ A,
                                                      const float* __restrict__ Bw,
                                                      const float* __restrict__ bias,
                                                      __half* __restrict__ C,
                                                      int M, int N, int K) {
  __shared__ __align__(16) float As[BKk][BM];
  __shared__ __align__(16) float Bs[BKk][BN];
  const int tid = threadIdx.x;
  const int bm = blockIdx.y * BM, bn = blockIdx.x * BN;
  const int ty = tid >> 4, tx = tid & 15;
  const int srow = tid >> 1;
  const int sk = (tid & 1) * 8;

  const float* Aptr = A + (size_t)(bm + srow) * K + sk;
  const float* Bptr = Bw + (size_t)(bn + srow) * K + sk;

  float4 ra0 = *(const float4*)(Aptr);
  float4 ra1 = *(const float4*)(Aptr + 4);
  float4 rb0 = *(const float4*)(Bptr);
  float4 rb1 = *(const float4*)(Bptr + 4);

  float acc[8][8];
#pragma unroll
  for (int i = 0; i < 8; ++i)
#pragma unroll
    for (int j = 0; j < 8; ++j) acc[i][j] = 0.0f;

  for (int k0 = 0; k0 < K; k0 += BKk) {
    __syncthreads();
    As[sk + 0][srow] = ra0.x; As[sk + 1][srow] = ra0.y;
    As[sk + 2][srow] = ra0.z; As[sk + 3][srow] = ra0.w;
    As[sk + 4][srow] = ra1.x; As[sk + 5][srow] = ra1.y;
    As[sk + 6][srow] = ra1.z; As[sk + 7][srow] = ra1.w;
    Bs[sk + 0][srow] = rb0.x; Bs[sk + 1][srow] = rb0.y;
    Bs[sk + 2][srow] = rb0.z; Bs[sk + 3][srow] = rb0.w;
    Bs[sk + 4][srow] = rb1.x; Bs[sk + 5][srow] = rb1.y;
    Bs[sk + 6][srow] = rb1.z; Bs[sk + 7][srow] = rb1.w;
    __syncthreads();
    if (k0 + BKk < K) {
      ra0 = *(const float4*)(Aptr + k0 + BKk);
      ra1 = *(const float4*)(Aptr + k0 + BKk + 4);
      rb0 = *(const float4*)(Bptr + k0 + BKk);
      rb1 = *(const float4*)(Bptr + k0 + BKk + 4);
    }
#pragma unroll
    for (int kk = 0; kk < BKk; ++kk) {
      float4 aA = *(const float4*)&As[kk][ty * 8];
      float4 aB = *(const float4*)&As[kk][ty * 8 + 4];
      float4 bA = *(const float4*)&Bs[kk][tx * 8];
      float4 bB = *(const float4*)&Bs[kk][tx * 8 + 4];
      float av[8] = {aA.x, aA.y, aA.z, aA.w, aB.x, aB.y, aB.z, aB.w};
      float bv[8] = {bA.x, bA.y, bA.z, bA.w, bB.x, bB.y, bB.z, bB.w};
#pragma unroll
      for (int i = 0; i < 8; ++i)
#pragma unroll
        for (int j = 0; j < 8; ++j)
          acc[i][j] = fmaf(av[i], bv[j], acc[i][j]);
    }
  }
  float bs[8];
#pragma unroll
  for (int j = 0; j < 8; ++j) bs[j] = bias[bn + tx * 8 + j];

  // scatter into scan fragment layout:
  // half idx = ((((t*4+b)*8+w)*2+z)*64 + lane)*16 + g*4 + j
  const int col0 = bn + tx * 8;
  const int g = col0 >> 8;
  const int u0 = col0 & 255;                 // 8-aligned
  const int w_ = u0 >> 5, z_ = (u0 >> 4) & 1, l15_ = u0 & 15;
#pragma unroll
  for (int i = 0; i < 8; ++i) {
    const int row = bm + ty * 8 + i;
    const int t = row & (Tt - 1);
    const int batch = row >> 9;
    const int b_ = batch >> 4, rbq = (batch & 15) >> 2, j_ = batch & 3;
    const int lane = (rbq << 4) | l15_;
    __half* dst = C + ((((size_t)t * 4 + b_) * 8 + w_) * 2 + z_) * 1024
                    + (size_t)lane * 16 + g * 4 + j_;
#pragma unroll
    for (int jx = 0; jx < 8; ++jx) dst[jx * 16] = __float2half(acc[i][jx] + bs[jx]);
  }
}

// ------ multi-block LSTM scan: 1 wave/block, 16 units x 16 rows per block -----
// grid = nfwd + nbwd blocks; per direction: 4 rowgroups x 16 unit-slices.
// B-fragments (this slice's Whh columns) live in 128 VGPRs for all 512 steps.
// h exchanged via global fp16 hex[s][row][unit]; per-step flags, device scope.
__global__ __launch_bounds__(64) void lstm_scan_sync(
    const half8_t* __restrict__ preF, const half8_t* __restrict__ wF,
    _Float16* __restrict__ hexF, int* __restrict__ flgF,
    const half8_t* __restrict__ preB, const half8_t* __restrict__ wB,
    _Float16* __restrict__ hexB, int* __restrict__ flgB, int nfwd) {
  const int isB = (blockIdx.x >= nfwd) ? 1 : 0;
  const half8_t* pre = isB ? preB : preF;
  const half8_t* wfrag = isB ? wB : wF;
  _Float16* hex = isB ? hexB : hexF;
  int* flg = isB ? flgB : flgF;
  const int bid = blockIdx.x - (isB ? nfwd : 0);
  const int rg = bid >> 4, sl = bid & 15;
  const int w_ = sl >> 1, z_ = sl & 1;
  const int l = threadIdx.x, l15 = l & 15, lg = l >> 4;
  const int u0 = sl * 16;

  // B fragments: resident for the whole scan (32 x half8 = 128 VGPR)
  half8_t bfr[8][4];
#pragma unroll
  for (int ks = 0; ks < 8; ++ks)
#pragma unroll
    for (int g = 0; g < 4; ++g)
      bfr[ks][g] = wfrag[(size_t)((w_ * 8 + ks) * 8 + z_ * 4 + g) * 64 + l];

  float c[4] = {0.f, 0.f, 0.f, 0.f};
  half8_t pc0, pc1;
  {
    const int t0 = isB ? (Tt - 1) : 0;
    const half8_t* pp = pre + ((size_t)(t0 * 4 + rg) * 16 + sl) * 128 + l * 2;
    pc0 = pp[0]; pc1 = pp[1];
  }

  for (int s = 0; s < Tt; ++s) {
    // acc init from prefetched pre (C/D: col=l15 -> unit, row=lg*4+j -> row)
    f32x4 acc[4];
#pragma unroll
    for (int g = 0; g < 4; ++g)
#pragma unroll
      for (int j = 0; j < 4; ++j)
        acc[g][j] = (float)((g < 2 ? pc0 : pc1)[(g & 1) * 4 + j]);

    // prefetch next step's pre (independent of the poll -> overlaps it)
    if (s + 1 < Tt) {
      const int tn = isB ? (Tt - 2 - s) : (s + 1);
      const half8_t* pp = pre + ((size_t)(tn * 4 + rg) * 16 + sl) * 128 + l * 2;
      pc0 = pp[0]; pc1 = pp[1];
    }

    if (s > 0) {
      // wait for all 16 slices of this rowgroup to publish h(s-1)
      const int* fb = flg + ((size_t)(s - 1) * 4 + rg) * 16;
      if (l < 16) {
        while (__hip_atomic_load(&fb[l], __ATOMIC_RELAXED, __HIP_MEMORY_SCOPE_AGENT) == 0)
          __builtin_amdgcn_s_sleep(1);
      }
      __threadfence();   // acquire: invalidate local caches before reading h

      // A fragments straight from global: row=l15, k=ks*32+lg*8+e
      const char* ab = (const char*)hex + (((size_t)(s - 1) * 64 + rg * 16) * 256) * 2;
      half8_t afr[8];
#pragma unroll
      for (int ks = 0; ks < 8; ++ks)
        afr[ks] = *(const half8_t*)(ab + l15 * 512 + ks * 64 + lg * 16);

#pragma unroll
      for (int ks = 0; ks < 8; ++ks)
#pragma unroll
        for (int g = 0; g < 4; ++g)
          acc[g] = __builtin_amdgcn_mfma_f32_16x16x32_f16(afr[ks], bfr[ks][g], acc[g], 0, 0, 0);
    }

    // gates -> c,h (i,f,g,o of each (row,unit) in-lane); publish h
#pragma unroll
    for (int j = 0; j < 4; ++j) {
      float iv = fsig(acc[0][j]);
      float fv = fsig(acc[1][j]);
      float gv = ftanh(acc[2][j]);
      float ov = fsig(acc[3][j]);
      c[j] = fv * c[j] + iv * gv;
      float hv = ov * ftanh(c[j]);
      hex[((size_t)s * 64 + rg * 16 + lg * 4 + j) * 256 + u0 + l15] = (_Float16)hv;
    }

    if (s < Tt - 1) {
      __threadfence();   // release: h stores reach coherence point
      if (l == 0)
        __hip_atomic_store(&flg[((size_t)s * 4 + rg) * 16 + sl], 1,
                           __ATOMIC_RELEASE, __HIP_MEMORY_SCOPE_AGENT);
    }
  }
}

// ---------------- VQ: 4 vectors/block, 128 threads (one code per thread) ------
// reads fp16 exchange buffers: hf at slot t, hb at slot 511-t
#define VPB 4
__global__ __launch_bounds__(128) void vq_kernel(const _Float16* __restrict__ hexF,
                                                 const _Float16* __restrict__ hexB,
                                                 const float* __restrict__ cb,
                                                 float* __restrict__ q,
                                                 float* __restrict__ dmin) {
  const int tid = threadIdx.x;
  const int v0 = blockIdx.x * VPB;
  __shared__ __align__(16) float zs[VPB][Ee];
  __shared__ float dsh[NCODE];
  __shared__ int ish[NCODE];
  __shared__ int best[VPB];

#pragma unroll
  for (int v = 0; v < VPB; ++v) {
    const int vv = v0 + v;
    const int b = vv >> 9, t = vv & 511;
    const _Float16* hf = hexF + ((size_t)t * 64 + b) * 256;
    const _Float16* hb = hexB + ((size_t)(Tt - 1 - t) * 64 + b) * 256;
    zs[v][tid]       = (float)hf[tid];
    zs[v][tid + 128] = (float)hf[tid + 128];
    zs[v][tid + 256] = (float)hb[tid];
    zs[v][tid + 384] = (float)hb[tid + 128];
  }
  __syncthreads();

  float dv[VPB] = {0.0f, 0.0f, 0.0f, 0.0f};
  const float4* crow = (const float4*)(cb + (size_t)tid * Ee);
#pragma unroll 2
  for (int e4 = 0; e4 < Ee / 4; ++e4) {
    float4 cc = crow[e4];
#pragma unroll
    for (int v = 0; v < VPB; ++v) {
      float4 z = *(const float4*)&zs[v][e4 * 4];
      float t0 = z.x - cc.x, t1 = z.y - cc.y, t2 = z.z - cc.z, t3 = z.w - cc.w;
      dv[v] = fmaf(t0, t0, dv[v]);
      dv[v] = fmaf(t1, t1, dv[v]);
      dv[v] = fmaf(t2, t2, dv[v]);
      dv[v] = fmaf(t3, t3, dv[v]);
    }
  }

#pragma unroll
  for (int v = 0; v < VPB; ++v) {
    __syncthreads();
    dsh[tid] = dv[v];
    ish[tid] = tid;
    __syncthreads();
    for (int off = 64; off > 0; off >>= 1) {
      if (tid < off) {
        float dn = dsh[tid + off];
        int in_ = ish[tid + off];
        if (dn < dsh[tid] || (dn == dsh[tid] && in_ < ish[tid])) {
          dsh[tid] = dn;
          ish[tid] = in_;
        }
      }
      __syncthreads();
    }
    if (tid == 0) {
      best[v] = ish[0];
      dmin[v0 + v] = dsh[0];
    }
  }
  __syncthreads();

#pragma unroll
  for (int v = 0; v < VPB; ++v) {
    const float* cbest = cb + (size_t)best[v] * Ee;
    float* qrow = q + (size_t)(v0 + v) * Ee;
#pragma unroll
    for (int u = 0; u < 4; ++u) {
      int e = tid + u * 128;
      float z = zs[v][e];
      qrow[e] = z + (cbest[e] - z);
    }
  }
}

// ---------------- vq loss reduce ----------------
__global__ __launch_bounds__(256) void vq_reduce(const float* __restrict__ dmin,
                                                 float* __restrict__ out) {
  __shared__ float sh[256];
  int tid = threadIdx.x;
  float s = 0.0f;
  for (int i = tid; i < Bb * Tt; i += 256) s += dmin[i];
  sh[tid] = s;
  __syncthreads();
  for (int off = 128; off > 0; off >>= 1) {
    if (tid < off) sh[tid] += sh[tid + off];
    __syncthreads();
  }
  if (tid == 0) out[Bb * NCLS] = sh[0] * (1.25f / ((float)(Bb * Tt) * (float)Ee));
}

// ---------------- decoder backward, single step at t=T-1 (h_prev=c_prev=0) ----
__global__ __launch_bounds__(256) void dec_bwd_last(const float* __restrict__ q,
                                                    const float* __restrict__ wpB,  // [512][256][4]
                                                    const float* __restrict__ bias,
                                                    float* __restrict__ hb_last) {
  int b = blockIdx.x, tid = threadIdx.x;
  __shared__ __align__(16) float zsl[Ee];
  const float* qrow = q + ((size_t)b * Tt + (Tt - 1)) * Ee;
  zsl[tid] = qrow[tid];
  zsl[tid + 256] = qrow[tid + 256];
  __syncthreads();
  float a0 = bias[tid], a1 = bias[256 + tid], a2 = bias[512 + tid], a3 = bias[768 + tid];
  const float4* wp4 = (const float4*)wpB;
#pragma unroll 4
  for (int k = 0; k < Ee; ++k) {
    float zk = zsl[k];
    float4 w = wp4[((size_t)k << 8) + tid];
    a0 = fmaf(zk, w.x, a0); a1 = fmaf(zk, w.y, a1);
    a2 = fmaf(zk, w.z, a2); a3 = fmaf(zk, w.w, a3);
  }
  float i = sigf(a0), f = sigf(a1), g = tanhf(a2), o = sigf(a3);
  (void)f;
  float cc = i * g;
  hb_last[b * Hh + tid] = o * tanhf(cc);
}

// ---------------- classifier ----------------
__global__ __launch_bounds__(256) void classifier_k(const _Float16* __restrict__ hexD,
                                                    const float* __restrict__ hb_last,
                                                    const float* __restrict__ Wcls,
                                                    const float* __restrict__ bcls,
                                                    float* __restrict__ out) {
  int b = blockIdx.x, tid = threadIdx.x;
  __shared__ __align__(16) float dl[Ee];
  dl[tid] = (float)hexD[((size_t)(Tt - 1) * 64 + b) * 256 + tid];
  dl[tid + 256] = hb_last[b * Hh + tid];
  __syncthreads();
  if (tid < NCLS) {
    const float4* wr = (const float4*)(Wcls + (size_t)tid * Ee);
    float acc = bcls[tid];
#pragma unroll 4
    for (int e4 = 0; e4 < Ee / 4; ++e4) {
      float4 w = wr[e4];
      float4 z = *(const float4*)&dl[e4 * 4];
      acc = fmaf(w.x, z.x, acc);
      acc = fmaf(w.y, z.y, acc);
      acc = fmaf(w.z, z.z, acc);
      acc = fmaf(w.w, z.w, acc);
    }
    out[b * NCLS + tid] = acc;
  }
}

// ---------------- launch ----------------
extern "C" void kernel_launch(void* const* d_in, const int* in_sizes, int n_in,
                              void* d_out, int out_size, void* d_ws, size_t ws_size,
                              hipStream_t stream) {
  const float* x     = (const float*)d_in[0];
  const float* eWihF = (const float*)d_in[1];
  const float* eWhhF = (const float*)d_in[2];
  const float* ebF   = (const float*)d_in[3];
  const float* eWihB = (const float*)d_in[4];
  const float* eWhhB = (const float*)d_in[5];
  const float* ebB   = (const float*)d_in[6];
  const float* cb    = (const float*)d_in[7];
  const float* dWihF = (const float*)d_in[8];
  const float* dWhhF = (const float*)d_in[9];
  const float* dbF   = (const float*)d_in[10];
  const float* dWihB = (const float*)d_in[11];
  // d_in[12] = dec_Whh_b: unused (backward decoder state at t=T-1 starts from zero)
  const float* dbB   = (const float*)d_in[13];
  const float* Wcls  = (const float*)d_in[14];
  const float* bcls  = (const float*)d_in[15];
  float* out = (float*)d_out;
  float* w = (float*)d_ws;

  const size_t MR = (size_t)Bb * Tt;                 // 32768
  const size_t SZ_PRE_H = MR * G4 / 2;               // fp16 pre buffer, float units
  const size_t SZ_HEX  = (size_t)Tt * Bb * Hh / 2;   // fp16 exchange, float units
  const size_t SZ_XPAD = MR * INPAD;
  const size_t SZ_WPAD = (size_t)G4 * INPAD;
  const size_t SZ_WPK  = (size_t)512 * G4;
  const size_t SZ_WPH  = (size_t)G4 * Hh / 2;        // fp16 frag pack, float units
  const int NFLG = Tt * 4 * 16;                      // per direction

  size_t o = 0;
  __half* preFh = (__half*)(w + o); o += SZ_PRE_H;
  __half* preBh = (__half*)(w + o); o += SZ_PRE_H;
  _Float16* hexF = (_Float16*)(w + o); o += SZ_HEX;
  _Float16* hexB = (_Float16*)(w + o); o += SZ_HEX;
  _Float16* hexD = (_Float16*)(w + o); o += SZ_HEX;
  int* flgF = (int*)(w + o); o += NFLG;
  int* flgB = (int*)(w + o); o += NFLG;
  int* flgD = (int*)(w + o); o += NFLG;
  float* xpad  = w + o; o += SZ_XPAD;
  float* wfpad = w + o; o += SZ_WPAD;
  float* wbpad = w + o; o += SZ_WPAD;
  float* wpkbd = w + o; o += SZ_WPK;
  _Float16* wphF = (_Float16*)(w + o); o += SZ_WPH;
  _Float16* wphB = (_Float16*)(w + o); o += SZ_WPH;
  _Float16* wphD = (_Float16*)(w + o); o += SZ_WPH;
  float* dminp = w + o; o += MR;
  float* hbl   = w + o; o += (size_t)Bb * Hh;
  // aliases over dead regions
  float* quant = (float*)preFh;      // 64 MB fp32 over dead enc preF
  __half* dprf = preBh;              // dec fp16 pre over dead enc preB

  // 1. flags + prep
  hipLaunchKernelGGL(zero_flags_k, dim3((3 * NFLG + 255) / 256), dim3(256), 0, stream,
                     flgF, 3 * NFLG);
  hipLaunchKernelGGL(pad_copy_k, dim3((MR * INPAD) / 256), dim3(256), 0, stream,
                     x, xpad, (int)MR, INRAW, INPAD);
  hipLaunchKernelGGL(pad_copy_k, dim3((G4 * INPAD) / 256), dim3(256), 0, stream,
                     eWihF, wfpad, G4, INRAW, INPAD);
  hipLaunchKernelGGL(pad_copy_k, dim3((G4 * INPAD) / 256), dim3(256), 0, stream,
                     eWihB, wbpad, G4, INRAW, INPAD);
  hipLaunchKernelGGL(pack_w_k, dim3((G4 * 512) / 256), dim3(256), 0, stream, dWihB, wpkbd, 512);
  hipLaunchKernelGGL(pack_w_frag, dim3(1024), dim3(256), 0, stream, eWhhF, wphF);
  hipLaunchKernelGGL(pack_w_frag, dim3(1024), dim3(256), 0, stream, eWhhB, wphB);
  hipLaunchKernelGGL(pack_w_frag, dim3(1024), dim3(256), 0, stream, dWhhF, wphD);

  // 2. encoder input projections
  const dim3 gemmGrid(G4 / BN, MR / BM);
  hipLaunchKernelGGL(gemm_nt_bias_h, gemmGrid, dim3(256), 0, stream,
                     xpad, wfpad, ebF, preFh, (int)MR, G4, INPAD);
  hipLaunchKernelGGL(gemm_nt_bias_h, gemmGrid, dim3(256), 0, stream,
                     xpad, wbpad, ebB, preBh, (int)MR, G4, INPAD);

  // 3. encoder scan: 128 one-wave blocks (64 fwd + 64 bwd)
  hipLaunchKernelGGL(lstm_scan_sync, dim3(128), dim3(64), 0, stream,
                     (const half8_t*)preFh, (const half8_t*)wphF, hexF, flgF,
                     (const half8_t*)preBh, (const half8_t*)wphB, hexB, flgB, 64);

  // 4. VQ + loss
  hipLaunchKernelGGL(vq_kernel, dim3(MR / VPB), dim3(128), 0, stream,
                     hexF, hexB, cb, quant, dminp);
  hipLaunchKernelGGL(vq_reduce, dim3(1), dim3(256), 0, stream, dminp, out);

  // 5. decoder fwd input projection
  hipLaunchKernelGGL(gemm_nt_bias_h, gemmGrid, dim3(256), 0, stream,
                     quant, dWihF, dbF, dprf, (int)MR, G4, Ee);

  // 6. decoder bwd (only t=T-1 contributes)
  hipLaunchKernelGGL(dec_bwd_last, dim3(Bb), dim3(256), 0, stream, quant, wpkbd, dbB, hbl);

  // 7. decoder fwd scan: 64 one-wave blocks
  hipLaunchKernelGGL(lstm_scan_sync, dim3(64), dim3(64), 0, stream,
                     (const half8_t*)dprf, (const half8_t*)wphD, hexD, flgD,
                     (const half8_t*)dprf, (const half8_t*)wphD, hexD, flgD, 64);

  // 8. classifier
  hipLaunchKernelGGL(classifier_k, dim3(Bb), dim3(256), 0, stream,
                     hexD, hbl, Wcls, bcls, out);
}

// Round 6
// 4753.474 us; speedup vs baseline: 2.0102x; 1.8027x over previous
//
#include <hip/hip_runtime.h>
#include <hip/hip_fp16.h>
#include <cstddef>

#define Bb 64
#define Tt 512
#define INRAW 225
#define INPAD 240
#define Hh 256
#define G4 1024
#define Ee 512
#define NCODE 128
#define NCLS 250

typedef _Float16 half8_t __attribute__((ext_vector_type(8)));
typedef float f32x4 __attribute__((ext_vector_type(4)));

__device__ __forceinline__ float sigf(float x) { return 1.0f / (1.0f + expf(-x)); }
__device__ __forceinline__ float fsig(float x) { return __builtin_amdgcn_rcpf(1.0f + __expf(-x)); }
__device__ __forceinline__ float ftanh(float x) {
  return 2.0f * __builtin_amdgcn_rcpf(1.0f + __expf(-2.0f * x)) - 1.0f;
}

// ---------------- zero flags ----------------
__global__ __launch_bounds__(256) void zero_flags_k(int* __restrict__ p, int n) {
  int i = blockIdx.x * 256 + threadIdx.x;
  if (i < n) __hip_atomic_store(&p[i], 0, __ATOMIC_RELAXED, __HIP_MEMORY_SCOPE_AGENT);
}

// ---------------- pad copy: [M,Ks] -> [M,Kd] zero-filled ----------------
__global__ __launch_bounds__(256) void pad_copy_k(const float* __restrict__ src,
                                                  float* __restrict__ dst,
                                                  int M, int Ks, int Kd) {
  long long idx = (long long)blockIdx.x * 256 + threadIdx.x;
  if (idx >= (long long)M * Kd) return;
  int m = (int)(idx / Kd);
  int k = (int)(idx - (long long)m * Kd);
  dst[idx] = (k < Ks) ? src[(long long)m * Ks + k] : 0.0f;
}

// ------- pack W[1024,K] -> wp[k][j(0..255)][g(0..3)] fp32 (dec_bwd only) ------
__global__ __launch_bounds__(256) void pack_w_k(const float* __restrict__ W,
                                                float* __restrict__ wp, int K) {
  int idx = blockIdx.x * 256 + threadIdx.x;   // = jg*K + k
  int jg = idx / K;
  if (jg >= 1024) return;
  int k = idx - jg * K;
  int j = jg >> 2, g = jg & 3;
  wp[(((size_t)k << 8) + j) * 4 + g] = W[(size_t)(g * 256 + j) * K + k];
}

// ------- pack Whh[1024,256] fp32 -> fp16 MFMA B-fragment stream ---------------
// flat half idx = ((((wv*8+ks)*8)+zg)*64 + l)*8 + e
// value = Whh[(g*256 + u)*256 + k], zg=z*4+g, u=wv*32+z*16+(l&15), k=ks*32+(l>>4)*8+e
__global__ __launch_bounds__(256) void pack_w_frag(const float* __restrict__ W,
                                                   _Float16* __restrict__ wp) {
  int idx = blockIdx.x * 256 + threadIdx.x;   // 262144 total
  int e = idx & 7, l = (idx >> 3) & 63, zg = (idx >> 9) & 7;
  int ks = (idx >> 12) & 7, wv = (idx >> 15) & 7;
  int z = zg >> 2, g = zg & 3;
  int u = wv * 32 + z * 16 + (l & 15);
  int k = ks * 32 + (l >> 4) * 8 + e;
  wp[idx] = (_Float16)W[(size_t)(g * 256 + u) * 256 + k];
}

// ---- GEMM: C[M,N] = A[M,K] @ Bw[N,K]^T + bias[N]; fp16 out in the scan's
// per-lane fragment order (verified R4).
#define BM 128
#define BN 128
#define BKk 16
__global__ __launch_bounds__(256) void gemm_nt_bias_h(const float* __restrict__ A,
                                                      const float* __restrict__ Bw,
                                                      const float* __restrict__ bias,
                                                      __half* __restrict__ C,
                                                      int M, int N, int K) {
  __shared__ __align__(16) float As[BKk][BM];
  __shared__ __align__(16) float Bs[BKk][BN];
  const int tid = threadIdx.x;
  const int bm = blockIdx.y * BM, bn = blockIdx.x * BN;
  const int ty = tid >> 4, tx = tid & 15;
  const int srow = tid >> 1;
  const int sk = (tid & 1) * 8;

  const float* Aptr = A + (size_t)(bm + srow) * K + sk;
  const float* Bptr = Bw + (size_t)(bn + srow) * K + sk;

  float4 ra0 = *(const float4*)(Aptr);
  float4 ra1 = *(const float4*)(Aptr + 4);
  float4 rb0 = *(const float4*)(Bptr);
  float4 rb1 = *(const float4*)(Bptr + 4);

  float acc[8][8];
#pragma unroll
  for (int i = 0; i < 8; ++i)
#pragma unroll
    for (int j = 0; j < 8; ++j) acc[i][j] = 0.0f;

  for (int k0 = 0; k0 < K; k0 += BKk) {
    __syncthreads();
    As[sk + 0][srow] = ra0.x; As[sk + 1][srow] = ra0.y;
    As[sk + 2][srow] = ra0.z; As[sk + 3][srow] = ra0.w;
    As[sk + 4][srow] = ra1.x; As[sk + 5][srow] = ra1.y;
    As[sk + 6][srow] = ra1.z; As[sk + 7][srow] = ra1.w;
    Bs[sk + 0][srow] = rb0.x; Bs[sk + 1][srow] = rb0.y;
    Bs[sk + 2][srow] = rb0.z; Bs[sk + 3][srow] = rb0.w;
    Bs[sk + 4][srow] = rb1.x; Bs[sk + 5][srow] = rb1.y;
    Bs[sk + 6][srow] = rb1.z; Bs[sk + 7][srow] = rb1.w;
    __syncthreads();
    if (k0 + BKk < K) {
      ra0 = *(const float4*)(Aptr + k0 + BKk);
      ra1 = *(const float4*)(Aptr + k0 + BKk + 4);
      rb0 = *(const float4*)(Bptr + k0 + BKk);
      rb1 = *(const float4*)(Bptr + k0 + BKk + 4);
    }
#pragma unroll
    for (int kk = 0; kk < BKk; ++kk) {
      float4 aA = *(const float4*)&As[kk][ty * 8];
      float4 aB = *(const float4*)&As[kk][ty * 8 + 4];
      float4 bA = *(const float4*)&Bs[kk][tx * 8];
      float4 bB = *(const float4*)&Bs[kk][tx * 8 + 4];
      float av[8] = {aA.x, aA.y, aA.z, aA.w, aB.x, aB.y, aB.z, aB.w};
      float bv[8] = {bA.x, bA.y, bA.z, bA.w, bB.x, bB.y, bB.z, bB.w};
#pragma unroll
      for (int i = 0; i < 8; ++i)
#pragma unroll
        for (int j = 0; j < 8; ++j)
          acc[i][j] = fmaf(av[i], bv[j], acc[i][j]);
    }
  }
  float bs[8];
#pragma unroll
  for (int j = 0; j < 8; ++j) bs[j] = bias[bn + tx * 8 + j];

  // scatter into scan fragment layout:
  // half idx = ((((t*4+b)*8+w)*2+z)*64 + lane)*16 + g*4 + j
  const int col0 = bn + tx * 8;
  const int g = col0 >> 8;
  const int u0 = col0 & 255;                 // 8-aligned
  const int w_ = u0 >> 5, z_ = (u0 >> 4) & 1, l15_ = u0 & 15;
#pragma unroll
  for (int i = 0; i < 8; ++i) {
    const int row = bm + ty * 8 + i;
    const int t = row & (Tt - 1);
    const int batch = row >> 9;
    const int b_ = batch >> 4, rbq = (batch & 15) >> 2, j_ = batch & 3;
    const int lane = (rbq << 4) | l15_;
    __half* dst = C + ((((size_t)t * 4 + b_) * 8 + w_) * 2 + z_) * 1024
                    + (size_t)lane * 16 + g * 4 + j_;
#pragma unroll
    for (int jx = 0; jx < 8; ++jx) dst[jx * 16] = __float2half(acc[i][jx] + bs[jx]);
  }
}

// ------ multi-block LSTM scan: 1 wave/block, 16 units x 16 rows per block -----
// h exchanged via sc0sc1 (agent-coherent) stores/loads; per-step flags; NO
// threadfence (no L2 invalidation -> pre/weights stay cached).
__global__ __launch_bounds__(64) void lstm_scan_sync(
    const half8_t* __restrict__ preF, const half8_t* __restrict__ wF,
    _Float16* __restrict__ hexF, int* __restrict__ flgF,
    const half8_t* __restrict__ preB, const half8_t* __restrict__ wB,
    _Float16* __restrict__ hexB, int* __restrict__ flgB, int nfwd) {
  const int isB = (blockIdx.x >= nfwd) ? 1 : 0;
  const half8_t* pre = isB ? preB : preF;
  const half8_t* wfrag = isB ? wB : wF;
  _Float16* hex = isB ? hexB : hexF;
  int* flg = isB ? flgB : flgF;
  const int bid = blockIdx.x - (isB ? nfwd : 0);
  const int rg = bid >> 4, sl = bid & 15;
  const int w_ = sl >> 1, z_ = sl & 1;
  const int l = threadIdx.x, l15 = l & 15, lg = l >> 4;
  const int u0 = sl * 16;

  // B fragments: resident for the whole scan (32 x half8 = 128 VGPR)
  half8_t bfr[8][4];
#pragma unroll
  for (int ks = 0; ks < 8; ++ks)
#pragma unroll
    for (int g = 0; g < 4; ++g)
      bfr[ks][g] = wfrag[(size_t)((w_ * 8 + ks) * 8 + z_ * 4 + g) * 64 + l];

  float c[4] = {0.f, 0.f, 0.f, 0.f};
  half8_t pc0, pc1;
  {
    const int t0 = isB ? (Tt - 1) : 0;
    const half8_t* pp = pre + ((size_t)(t0 * 4 + rg) * 16 + sl) * 128 + l * 2;
    pc0 = pp[0]; pc1 = pp[1];
  }

  for (int s = 0; s < Tt; ++s) {
    // acc init from prefetched pre (C/D: col=l15 -> unit, row=lg*4+j -> row)
    f32x4 acc[4];
#pragma unroll
    for (int g = 0; g < 4; ++g)
#pragma unroll
      for (int j = 0; j < 4; ++j)
        acc[g][j] = (float)((g < 2 ? pc0 : pc1)[(g & 1) * 4 + j]);

    // prefetch next step's pre (normal cached loads; overlap the poll)
    if (s + 1 < Tt) {
      const int tn = isB ? (Tt - 2 - s) : (s + 1);
      const half8_t* pp = pre + ((size_t)(tn * 4 + rg) * 16 + sl) * 128 + l * 2;
      pc0 = pp[0]; pc1 = pp[1];
    }

    if (s > 0) {
      // wait for all 16 slices of this rowgroup to publish h(s-1)
      int* fb = flg + ((size_t)(s - 1) * 4 + rg) * 16;
      if (l < 16) {
        while (__hip_atomic_load(&fb[l], __ATOMIC_RELAXED, __HIP_MEMORY_SCOPE_AGENT) == 0)
          __builtin_amdgcn_s_sleep(1);
      }
      // coherent reads bypass L1/L2 (no cache invalidation needed)
      const char* ab = (const char*)hex + (((size_t)(s - 1) * 64 + rg * 16) * 256) * 2;
      half8_t afr[8];
#pragma unroll
      for (int ks = 0; ks < 8; ++ks) {
        const void* ap = (const void*)(ab + l15 * 512 + ks * 64 + lg * 16);
        asm volatile("global_load_dwordx4 %0, %1, off sc0 sc1"
                     : "=v"(afr[ks]) : "v"(ap) : "memory");
      }
      asm volatile("s_waitcnt vmcnt(0)" ::: "memory");
      __builtin_amdgcn_sched_barrier(0);

#pragma unroll
      for (int ks = 0; ks < 8; ++ks)
#pragma unroll
        for (int g = 0; g < 4; ++g)
          acc[g] = __builtin_amdgcn_mfma_f32_16x16x32_f16(afr[ks], bfr[ks][g], acc[g], 0, 0, 0);
    }

    // gates -> c,h; publish h via agent-coherent short stores
#pragma unroll
    for (int j = 0; j < 4; ++j) {
      float iv = fsig(acc[0][j]);
      float fv = fsig(acc[1][j]);
      float gv = ftanh(acc[2][j]);
      float ov = fsig(acc[3][j]);
      c[j] = fv * c[j] + iv * gv;
      float hv = ov * ftanh(c[j]);
      union { _Float16 f; unsigned short u; } cv;
      cv.f = (_Float16)hv;
      unsigned hb32 = cv.u;
      const void* hp = (const void*)(hex + ((size_t)s * 64 + rg * 16 + lg * 4 + j) * 256
                                     + u0 + l15);
      asm volatile("global_store_short %0, %1, off sc0 sc1"
                   :: "v"(hp), "v"(hb32) : "memory");
    }

    if (s < Tt - 1) {
      asm volatile("s_waitcnt vmcnt(0)" ::: "memory");  // h stores acked at L3
      if (l == 0)
        __hip_atomic_store(&flg[((size_t)s * 4 + rg) * 16 + sl], 1,
                           __ATOMIC_RELEASE, __HIP_MEMORY_SCOPE_AGENT);
    }
  }
}

// ---------------- VQ: 4 vectors/block, 128 threads (one code per thread) ------
#define VPB 4
__global__ __launch_bounds__(128) void vq_kernel(const _Float16* __restrict__ hexF,
                                                 const _Float16* __restrict__ hexB,
                                                 const float* __restrict__ cb,
                                                 float* __restrict__ q,
                                                 float* __restrict__ dmin) {
  const int tid = threadIdx.x;
  const int v0 = blockIdx.x * VPB;
  __shared__ __align__(16) float zs[VPB][Ee];
  __shared__ float dsh[NCODE];
  __shared__ int ish[NCODE];
  __shared__ int best[VPB];

#pragma unroll
  for (int v = 0; v < VPB; ++v) {
    const int vv = v0 + v;
    const int b = vv >> 9, t = vv & 511;
    const _Float16* hf = hexF + ((size_t)t * 64 + b) * 256;
    const _Float16* hb = hexB + ((size_t)(Tt - 1 - t) * 64 + b) * 256;
    zs[v][tid]       = (float)hf[tid];
    zs[v][tid + 128] = (float)hf[tid + 128];
    zs[v][tid + 256] = (float)hb[tid];
    zs[v][tid + 384] = (float)hb[tid + 128];
  }
  __syncthreads();

  float dv[VPB] = {0.0f, 0.0f, 0.0f, 0.0f};
  const float4* crow = (const float4*)(cb + (size_t)tid * Ee);
#pragma unroll 2
  for (int e4 = 0; e4 < Ee / 4; ++e4) {
    float4 cc = crow[e4];
#pragma unroll
    for (int v = 0; v < VPB; ++v) {
      float4 z = *(const float4*)&zs[v][e4 * 4];
      float t0 = z.x - cc.x, t1 = z.y - cc.y, t2 = z.z - cc.z, t3 = z.w - cc.w;
      dv[v] = fmaf(t0, t0, dv[v]);
      dv[v] = fmaf(t1, t1, dv[v]);
      dv[v] = fmaf(t2, t2, dv[v]);
      dv[v] = fmaf(t3, t3, dv[v]);
    }
  }

#pragma unroll
  for (int v = 0; v < VPB; ++v) {
    __syncthreads();
    dsh[tid] = dv[v];
    ish[tid] = tid;
    __syncthreads();
    for (int off = 64; off > 0; off >>= 1) {
      if (tid < off) {
        float dn = dsh[tid + off];
        int in_ = ish[tid + off];
        if (dn < dsh[tid] || (dn == dsh[tid] && in_ < ish[tid])) {
          dsh[tid] = dn;
          ish[tid] = in_;
        }
      }
      __syncthreads();
    }
    if (tid == 0) {
      best[v] = ish[0];
      dmin[v0 + v] = dsh[0];
    }
  }
  __syncthreads();

#pragma unroll
  for (int v = 0; v < VPB; ++v) {
    const float* cbest = cb + (size_t)best[v] * Ee;
    float* qrow = q + (size_t)(v0 + v) * Ee;
#pragma unroll
    for (int u = 0; u < 4; ++u) {
      int e = tid + u * 128;
      float z = zs[v][e];
      qrow[e] = z + (cbest[e] - z);
    }
  }
}

// ---------------- vq loss reduce ----------------
__global__ __launch_bounds__(256) void vq_reduce(const float* __restrict__ dmin,
                                                 float* __restrict__ out) {
  __shared__ float sh[256];
  int tid = threadIdx.x;
  float s = 0.0f;
  for (int i = tid; i < Bb * Tt; i += 256) s += dmin[i];
  sh[tid] = s;
  __syncthreads();
  for (int off = 128; off > 0; off >>= 1) {
    if (tid < off) sh[tid] += sh[tid + off];
    __syncthreads();
  }
  if (tid == 0) out[Bb * NCLS] = sh[0] * (1.25f / ((float)(Bb * Tt) * (float)Ee));
}

// ---------------- decoder backward, single step at t=T-1 (h_prev=c_prev=0) ----
__global__ __launch_bounds__(256) void dec_bwd_last(const float* __restrict__ q,
                                                    const float* __restrict__ wpB,  // [512][256][4]
                                                    const float* __restrict__ bias,
                                                    float* __restrict__ hb_last) {
  int b = blockIdx.x, tid = threadIdx.x;
  __shared__ __align__(16) float zsl[Ee];
  const float* qrow = q + ((size_t)b * Tt + (Tt - 1)) * Ee;
  zsl[tid] = qrow[tid];
  zsl[tid + 256] = qrow[tid + 256];
  __syncthreads();
  float a0 = bias[tid], a1 = bias[256 + tid], a2 = bias[512 + tid], a3 = bias[768 + tid];
  const float4* wp4 = (const float4*)wpB;
#pragma unroll 4
  for (int k = 0; k < Ee; ++k) {
    float zk = zsl[k];
    float4 w = wp4[((size_t)k << 8) + tid];
    a0 = fmaf(zk, w.x, a0); a1 = fmaf(zk, w.y, a1);
    a2 = fmaf(zk, w.z, a2); a3 = fmaf(zk, w.w, a3);
  }
  float i = sigf(a0), f = sigf(a1), g = tanhf(a2), o = sigf(a3);
  (void)f;
  float cc = i * g;
  hb_last[b * Hh + tid] = o * tanhf(cc);
}

// ---------------- classifier ----------------
__global__ __launch_bounds__(256) void classifier_k(const _Float16* __restrict__ hexD,
                                                    const float* __restrict__ hb_last,
                                                    const float* __restrict__ Wcls,
                                                    const float* __restrict__ bcls,
                                                    float* __restrict__ out) {
  int b = blockIdx.x, tid = threadIdx.x;
  __shared__ __align__(16) float dl[Ee];
  dl[tid] = (float)hexD[((size_t)(Tt - 1) * 64 + b) * 256 + tid];
  dl[tid + 256] = hb_last[b * Hh + tid];
  __syncthreads();
  if (tid < NCLS) {
    const float4* wr = (const float4*)(Wcls + (size_t)tid * Ee);
    float acc = bcls[tid];
#pragma unroll 4
    for (int e4 = 0; e4 < Ee / 4; ++e4) {
      float4 w = wr[e4];
      float4 z = *(const float4*)&dl[e4 * 4];
      acc = fmaf(w.x, z.x, acc);
      acc = fmaf(w.y, z.y, acc);
      acc = fmaf(w.z, z.z, acc);
      acc = fmaf(w.w, z.w, acc);
    }
    out[b * NCLS + tid] = acc;
  }
}

// ---------------- launch ----------------
extern "C" void kernel_launch(void* const* d_in, const int* in_sizes, int n_in,
                              void* d_out, int out_size, void* d_ws, size_t ws_size,
                              hipStream_t stream) {
  const float* x     = (const float*)d_in[0];
  const float* eWihF = (const float*)d_in[1];
  const float* eWhhF = (const float*)d_in[2];
  const float* ebF   = (const float*)d_in[3];
  const float* eWihB = (const float*)d_in[4];
  const float* eWhhB = (const float*)d_in[5];
  const float* ebB   = (const float*)d_in[6];
  const float* cb    = (const float*)d_in[7];
  const float* dWihF = (const float*)d_in[8];
  const float* dWhhF = (const float*)d_in[9];
  const float* dbF   = (const float*)d_in[10];
  const float* dWihB = (const float*)d_in[11];
  // d_in[12] = dec_Whh_b: unused (backward decoder state at t=T-1 starts from zero)
  const float* dbB   = (const float*)d_in[13];
  const float* Wcls  = (const float*)d_in[14];
  const float* bcls  = (const float*)d_in[15];
  float* out = (float*)d_out;
  float* w = (float*)d_ws;

  const size_t MR = (size_t)Bb * Tt;                 // 32768
  const size_t SZ_PRE_H = MR * G4 / 2;               // fp16 pre buffer, float units
  const size_t SZ_HEX  = (size_t)Tt * Bb * Hh / 2;   // fp16 exchange, float units
  const size_t SZ_XPAD = MR * INPAD;
  const size_t SZ_WPAD = (size_t)G4 * INPAD;
  const size_t SZ_WPK  = (size_t)512 * G4;
  const size_t SZ_WPH  = (size_t)G4 * Hh / 2;        // fp16 frag pack, float units
  const int NFLG = Tt * 4 * 16;                      // per direction

  size_t o = 0;
  __half* preFh = (__half*)(w + o); o += SZ_PRE_H;
  __half* preBh = (__half*)(w + o); o += SZ_PRE_H;
  _Float16* hexF = (_Float16*)(w + o); o += SZ_HEX;
  _Float16* hexB = (_Float16*)(w + o); o += SZ_HEX;
  _Float16* hexD = (_Float16*)(w + o); o += SZ_HEX;
  int* flgF = (int*)(w + o); o += NFLG;
  int* flgB = (int*)(w + o); o += NFLG;
  int* flgD = (int*)(w + o); o += NFLG;
  float* xpad  = w + o; o += SZ_XPAD;
  float* wfpad = w + o; o += SZ_WPAD;
  float* wbpad = w + o; o += SZ_WPAD;
  float* wpkbd = w + o; o += SZ_WPK;
  _Float16* wphF = (_Float16*)(w + o); o += SZ_WPH;
  _Float16* wphB = (_Float16*)(w + o); o += SZ_WPH;
  _Float16* wphD = (_Float16*)(w + o); o += SZ_WPH;
  float* dminp = w + o; o += MR;
  float* hbl   = w + o; o += (size_t)Bb * Hh;
  // aliases over dead regions
  float* quant = (float*)preFh;      // 64 MB fp32 over dead enc preF
  __half* dprf = preBh;              // dec fp16 pre over dead enc preB

  // 1. flags + prep
  hipLaunchKernelGGL(zero_flags_k, dim3((3 * NFLG + 255) / 256), dim3(256), 0, stream,
                     flgF, 3 * NFLG);
  hipLaunchKernelGGL(pad_copy_k, dim3((MR * INPAD) / 256), dim3(256), 0, stream,
                     x, xpad, (int)MR, INRAW, INPAD);
  hipLaunchKernelGGL(pad_copy_k, dim3((G4 * INPAD) / 256), dim3(256), 0, stream,
                     eWihF, wfpad, G4, INRAW, INPAD);
  hipLaunchKernelGGL(pad_copy_k, dim3((G4 * INPAD) / 256), dim3(256), 0, stream,
                     eWihB, wbpad, G4, INRAW, INPAD);
  hipLaunchKernelGGL(pack_w_k, dim3((G4 * 512) / 256), dim3(256), 0, stream, dWihB, wpkbd, 512);
  hipLaunchKernelGGL(pack_w_frag, dim3(1024), dim3(256), 0, stream, eWhhF, wphF);
  hipLaunchKernelGGL(pack_w_frag, dim3(1024), dim3(256), 0, stream, eWhhB, wphB);
  hipLaunchKernelGGL(pack_w_frag, dim3(1024), dim3(256), 0, stream, dWhhF, wphD);

  // 2. encoder input projections
  const dim3 gemmGrid(G4 / BN, MR / BM);
  hipLaunchKernelGGL(gemm_nt_bias_h, gemmGrid, dim3(256), 0, stream,
                     xpad, wfpad, ebF, preFh, (int)MR, G4, INPAD);
  hipLaunchKernelGGL(gemm_nt_bias_h, gemmGrid, dim3(256), 0, stream,
                     xpad, wbpad, ebB, preBh, (int)MR, G4, INPAD);

  // 3. encoder scan: 128 one-wave blocks (64 fwd + 64 bwd)
  hipLaunchKernelGGL(lstm_scan_sync, dim3(128), dim3(64), 0, stream,
                     (const half8_t*)preFh, (const half8_t*)wphF, hexF, flgF,
                     (const half8_t*)preBh, (const half8_t*)wphB, hexB, flgB, 64);

  // 4. VQ + loss
  hipLaunchKernelGGL(vq_kernel, dim3(MR / VPB), dim3(128), 0, stream,
                     hexF, hexB, cb, quant, dminp);
  hipLaunchKernelGGL(vq_reduce, dim3(1), dim3(256), 0, stream, dminp, out);

  // 5. decoder fwd input projection
  hipLaunchKernelGGL(gemm_nt_bias_h, gemmGrid, dim3(256), 0, stream,
                     quant, dWihF, dbF, dprf, (int)MR, G4, Ee);

  // 6. decoder bwd (only t=T-1 contributes)
  hipLaunchKernelGGL(dec_bwd_last, dim3(Bb), dim3(256), 0, stream, quant, wpkbd, dbB, hbl);

  // 7. decoder fwd scan: 64 one-wave blocks
  hipLaunchKernelGGL(lstm_scan_sync, dim3(64), dim3(64), 0, stream,
                     (const half8_t*)dprf, (const half8_t*)wphD, hexD, flgD,
                     (const half8_t*)dprf, (const half8_t*)wphD, hexD, flgD, 64);

  // 8. classifier
  hipLaunchKernelGGL(classifier_k, dim3(Bb), dim3(256), 0, stream,
                     hexD, hbl, Wcls, bcls, out);
}